// Round 11
// baseline (2512.340 us; speedup 1.0000x reference)
//
#include <hip/hip_runtime.h>
#include <cstdint>
#include <cstddef>

// Problem constants
#define B_    16
#define N_    512
#define L_    2048
#define DIM_  768
#define M_    8
#define CE_   64
#define VOCAB_ 1024
#define H_    128
#define G4_   512   // 4*H
#define XDIM_ 128   // 2*CE

typedef __bf16 bf16x8 __attribute__((ext_vector_type(8)));
typedef float  f32x4  __attribute__((ext_vector_type(4)));

__device__ __forceinline__ unsigned short f2bf(float f) {
    unsigned u = __float_as_uint(f);
    u += 0x7fffu + ((u >> 16) & 1u);   // RNE
    return (unsigned short)(u >> 16);
}

// ---------------------------------------------------------------------------
// Generic fp32 tiled GEMM: C[M,N] = A[M,K] @ B + bias1 (+bias2)
//   TRANSB=false: B is [K,N] row-major.  TRANSB=true: B is [N,K] row-major.
// 128x128 tile, BK=8, 256 threads, 8x8 per thread. R6: double-buffered LDS,
// one barrier per K-step, next-tile loads issued before compute.
// ---------------------------------------------------------------------------
template<bool TRANSB>
__global__ __launch_bounds__(256) void gemm_f32(
    const float* __restrict__ A, const float* __restrict__ Bm,
    const float* __restrict__ bias1, const float* __restrict__ bias2,
    float* __restrict__ C, int M, int N, int K)
{
    __shared__ float As[2][8][128];
    __shared__ float Bs[2][8][128];
    const int t  = threadIdx.x;
    const int tx = t & 15, ty = t >> 4;
    const int m0 = blockIdx.y * 128, n0 = blockIdx.x * 128;
    const int arow = t >> 1, ahalf = (t & 1) * 4;
    const int bk = t >> 5, bn = (t & 31) * 4;

    float acc[8][8];
#pragma unroll
    for (int i = 0; i < 8; i++)
#pragma unroll
        for (int j = 0; j < 8; j++) acc[i][j] = 0.f;

    {
        float4 av = *(const float4*)(A + (size_t)(m0 + arow) * K + ahalf);
        float4 bv;
        if (TRANSB) bv = *(const float4*)(Bm + (size_t)(n0 + arow) * K + ahalf);
        else        bv = *(const float4*)(Bm + (size_t)bk * N + n0 + bn);
        As[0][ahalf + 0][arow] = av.x;
        As[0][ahalf + 1][arow] = av.y;
        As[0][ahalf + 2][arow] = av.z;
        As[0][ahalf + 3][arow] = av.w;
        if (TRANSB) {
            Bs[0][ahalf + 0][arow] = bv.x;
            Bs[0][ahalf + 1][arow] = bv.y;
            Bs[0][ahalf + 2][arow] = bv.z;
            Bs[0][ahalf + 3][arow] = bv.w;
        } else {
            *(float4*)&Bs[0][bk][bn] = bv;
        }
    }
    __syncthreads();

    int cur = 0;
    for (int k0 = 0; k0 < K; k0 += 8) {
        const bool more = (k0 + 8 < K);
        float4 av, bv;
        if (more) {
            av = *(const float4*)(A + (size_t)(m0 + arow) * K + (k0 + 8) + ahalf);
            if (TRANSB) bv = *(const float4*)(Bm + (size_t)(n0 + arow) * K + (k0 + 8) + ahalf);
            else        bv = *(const float4*)(Bm + (size_t)(k0 + 8 + bk) * N + n0 + bn);
        }
#pragma unroll
        for (int k = 0; k < 8; k++) {
            float a[8], bb[8];
            *(float4*)&a[0]  = *(const float4*)&As[cur][k][ty * 8];
            *(float4*)&a[4]  = *(const float4*)&As[cur][k][ty * 8 + 4];
            *(float4*)&bb[0] = *(const float4*)&Bs[cur][k][tx * 8];
            *(float4*)&bb[4] = *(const float4*)&Bs[cur][k][tx * 8 + 4];
#pragma unroll
            for (int i = 0; i < 8; i++)
#pragma unroll
                for (int j = 0; j < 8; j++)
                    acc[i][j] = fmaf(a[i], bb[j], acc[i][j]);
        }
        if (more) {
            const int nxt = cur ^ 1;
            As[nxt][ahalf + 0][arow] = av.x;
            As[nxt][ahalf + 1][arow] = av.y;
            As[nxt][ahalf + 2][arow] = av.z;
            As[nxt][ahalf + 3][arow] = av.w;
            if (TRANSB) {
                Bs[nxt][ahalf + 0][arow] = bv.x;
                Bs[nxt][ahalf + 1][arow] = bv.y;
                Bs[nxt][ahalf + 2][arow] = bv.z;
                Bs[nxt][ahalf + 3][arow] = bv.w;
            } else {
                *(float4*)&Bs[nxt][bk][bn] = bv;
            }
        }
        __syncthreads();
        cur ^= 1;
    }

    float bia[8];
#pragma unroll
    for (int j = 0; j < 8; j++) {
        int gn = n0 + tx * 8 + j;
        bia[j] = bias1[gn] + (bias2 ? bias2[gn] : 0.f);
    }
#pragma unroll
    for (int i = 0; i < 8; i++) {
        size_t row = (size_t)(m0 + ty * 8 + i) * N + n0 + tx * 8;
#pragma unroll
        for (int j = 0; j < 8; j++)
            C[row + j] = acc[i][j] + bia[j];
    }
}

// ---------------------------------------------------------------------------
// Exclusive scan of word lengths per batch (N_=512 words, one block per batch)
// ---------------------------------------------------------------------------
__global__ __launch_bounds__(512) void scan_lens(const int* __restrict__ lens,
                                                 int* __restrict__ off)
{
    const int b = blockIdx.x, t = threadIdx.x;
    __shared__ int s[512];
    int v = lens[b * N_ + t];
    s[t] = v;
    __syncthreads();
    for (int d = 1; d < 512; d <<= 1) {
        int u = (t >= d) ? s[t - d] : 0;
        __syncthreads();
        s[t] += u;
        __syncthreads();
    }
    off[b * N_ + t] = s[t] - v;   // exclusive prefix
}

// ---------------------------------------------------------------------------
// dec_char gather + zero-fill of the pad half (replaces the 16 MB memset)
// ---------------------------------------------------------------------------
__global__ __launch_bounds__(256) void char_gather(const int* __restrict__ ids,
                                                   const float* __restrict__ emb,
                                                   float* __restrict__ x)
{
    int g   = blockIdx.x * 8 + (threadIdx.x >> 5);   // (b,l) flat, 8 per block
    int l32 = threadIdx.x & 31;
    int id  = ids[g];
    float4 v;
    if (l32 < 16) v = *(const float4*)(emb + (size_t)id * CE_ + l32 * 4);
    else          v = make_float4(0.f, 0.f, 0.f, 0.f);
    *(float4*)(x + (size_t)g * XDIM_ + l32 * 4) = v;
}

// ---------------------------------------------------------------------------
// Ragged scatter: x[b, off+m, 64+c] = rep[b,n,m,c] for m < len, off+m < L
// ---------------------------------------------------------------------------
__global__ __launch_bounds__(512) void scatter_pad(const float* __restrict__ rep,
                                                   const int* __restrict__ lens,
                                                   const int* __restrict__ off,
                                                   float* __restrict__ x)
{
    int word = blockIdx.x;            // b*512 + n
    int b = word >> 9;
    int m  = threadIdx.x >> 6;
    int cc = threadIdx.x & 63;
    int len = lens[word];
    if (m < len) {
        int dst = off[word] + m;
        if (dst < L_) {
            x[((size_t)b * L_ + dst) * XDIM_ + CE_ + cc] =
                rep[((size_t)word * M_ + m) * CE_ + cc];
        }
    }
}

// ---------------------------------------------------------------------------
// LSTM recurrence, R9 (resubmitted after infra failure): TWO-BATCH
// INSTRUCTION-STREAM INTERLEAVE + QUAD-SPLIT ACTIVATIONS. 8 blocks x 512 thr
// (8 waves, 2/SIMD); block runs batches 2b (=0) and 2b+1 (=1), phase-offset
// by half a step:
//   interval A(t): MFMA batch0 step t   || activations batch1 step t
//   interval B(t): MFMA batch1 step t+1 || activations batch0 step t
// Each interval's serial activation spine is covered by the partner batch's
// MFMA/ds_read issue IN THE SAME WAVE (explicit anti-phasing; R4's scheduler
// phase-lock does not apply). One barrier per interval.
//
// Quad-split: after MFMA, all 4 quads hold identical gate values. Quad q
// computes only sigma/tanh of gate q (uniform code: tanh = 2*sigma(2x)-1 via
// per-lane constants), then 4 ds_bpermute pulls gather {si,sf,tg,so} to all
// lanes. Per-wave trans ops 10 -> 4; the bpermute latency sits on the spine,
// which is hidden under the partner's MFMA issue.
//
// Prologue trick: batch1's step-0 MFMA is skipped (h_-1 = 0 => gates = gx
// preact folded into C-in reg0). Accs persistent: regs 1..3 never read.
// Evidence chain: R6 step 1085 = 480 issue + 530 serial; R7 proved 1 wave/
// SIMD exposes serial fully; R8 diet -> 1010. Interleave fills the 530;
// split cuts issue ~100/SIMD.
// ---------------------------------------------------------------------------
__global__ __launch_bounds__(512, 2) void lstm_rec(const float* __restrict__ gx,   // [B,L,512]
                                                   const float* __restrict__ Whh,  // [512,128]
                                                   float* __restrict__ hs)         // [B,L,128]
{
    const int blk  = blockIdx.x;
    const int tid  = threadIdx.x;
    const int wave = tid >> 6, lane = tid & 63;
    const int quad = lane >> 4, l15 = lane & 15;
    const int j    = wave * 16 + l15;          // hidden index owned by this lane

    __shared__ __align__(16) unsigned short hbuf[2][2][128];   // [batch][plane][j]
    if (tid < 128) { hbuf[0][0][tid] = 0; hbuf[1][0][tid] = 0; }  // h_{-1}=0

    // B fragments (shared by both batches): bfrag[q][kk] =
    //   W_hh[q*128 + j][kk*32 + quad*8 + 0..7] as bf16
    bf16x8 bfrag[4][4];
#pragma unroll
    for (int q = 0; q < 4; q++) {
        const float* wrow = Whh + (size_t)(q * 128 + j) * H_;
#pragma unroll
        for (int kk = 0; kk < 4; kk++) {
            int kb = kk * 32 + quad * 8;
            float4 w0 = *(const float4*)(wrow + kb);
            float4 w1 = *(const float4*)(wrow + kb + 4);
            union { unsigned short u[8]; bf16x8 v; } U;
            U.u[0] = f2bf(w0.x); U.u[1] = f2bf(w0.y); U.u[2] = f2bf(w0.z); U.u[3] = f2bf(w0.w);
            U.u[4] = f2bf(w1.x); U.u[5] = f2bf(w1.y); U.u[6] = f2bf(w1.z); U.u[7] = f2bf(w1.w);
            bfrag[q][kk] = U.v;
        }
    }

    // per-lane activation constants (quad 2 owns the tanh gate g)
    const float scale = (quad == 2) ? 2.f : 1.f;
    const float postm = (quad == 2) ? 2.f : 1.f;
    const float posta = (quad == 2) ? -1.f : 0.f;
    // bpermute byte-addresses: pull own-gate results from absolute quads 0..3
    const int ad0 = (0 * 16 + l15) * 4;
    const int ad1 = (1 * 16 + l15) * 4;
    const int ad2 = (2 * 16 + l15) * 4;
    const int ad3 = (3 * 16 + l15) * 4;

    // gx pointers + depth-4 preact rings per batch (lead = 4 rows)
    const float* gp2[2] = { gx + (size_t)(blk * 2 + 0) * L_ * G4_ + j,
                            gx + (size_t)(blk * 2 + 1) * L_ * G4_ + j };
    float pf[2][4][4];   // [batch][slot][gate]
#pragma unroll
    for (int bb = 0; bb < 2; bb++) {
#pragma unroll
        for (int u = 0; u < 4; u++)
#pragma unroll
            for (int q = 0; q < 4; q++)
                pf[bb][u][q] = gp2[bb][(size_t)u * G4_ + q * 128];
        gp2[bb] += 4 * G4_;
    }

    // persistent accumulators; consume slot 0 (step 0 preacts) for BOTH
    // batches here (batch1's step-0 MFMA is skipped: W @ 0 contributes 0),
    // then refill slot 0 with row 4.
    f32x4 acc[2][4];
#pragma unroll
    for (int bb = 0; bb < 2; bb++) {
#pragma unroll
        for (int q = 0; q < 4; q++) {
            acc[bb][q] = f32x4{pf[bb][0][q], 0.f, 0.f, 0.f};
            pf[bb][0][q] = gp2[bb][q * 128];
        }
        gp2[bb] += G4_;
    }

    float  c2[2]  = {0.f, 0.f};
    float* hp2[2] = { hs + (size_t)(blk * 2 + 0) * L_ * H_ + j,
                      hs + (size_t)(blk * 2 + 1) * L_ * H_ + j };

    __syncthreads();   // hbuf init visible

#define RCP_(x) __builtin_amdgcn_rcpf(x)
#define MFMA_(a, bb, cc) __builtin_amdgcn_mfma_f32_16x16x32_bf16(a, bb, cc, 0, 0, 0)
// One barrier interval: MFMA phase for batch MB (reads hbuf[MB][RP]),
// activation phase for batch AB (h written to hbuf[AB][WP]); then prep AB's
// next MFMA (C-in reg0 = preact from ring slot SLOT, refill slot, advance).
#define INTERVAL(MB, AB, RP, WP, SLOT)                                        \
    {                                                                         \
        bf16x8 a0 = *(const bf16x8*)&hbuf[MB][RP][ 0 + quad * 8];             \
        bf16x8 a1 = *(const bf16x8*)&hbuf[MB][RP][32 + quad * 8];             \
        bf16x8 a2 = *(const bf16x8*)&hbuf[MB][RP][64 + quad * 8];             \
        bf16x8 a3 = *(const bf16x8*)&hbuf[MB][RP][96 + quad * 8];             \
        acc[MB][0] = MFMA_(a0, bfrag[0][0], acc[MB][0]);                      \
        acc[MB][1] = MFMA_(a0, bfrag[1][0], acc[MB][1]);                      \
        acc[MB][2] = MFMA_(a0, bfrag[2][0], acc[MB][2]);                      \
        acc[MB][3] = MFMA_(a0, bfrag[3][0], acc[MB][3]);                      \
        acc[MB][0] = MFMA_(a1, bfrag[0][1], acc[MB][0]);                      \
        acc[MB][1] = MFMA_(a1, bfrag[1][1], acc[MB][1]);                      \
        acc[MB][2] = MFMA_(a1, bfrag[2][1], acc[MB][2]);                      \
        acc[MB][3] = MFMA_(a1, bfrag[3][1], acc[MB][3]);                      \
        acc[MB][0] = MFMA_(a2, bfrag[0][2], acc[MB][0]);                      \
        acc[MB][1] = MFMA_(a2, bfrag[1][2], acc[MB][1]);                      \
        acc[MB][2] = MFMA_(a2, bfrag[2][2], acc[MB][2]);                      \
        acc[MB][3] = MFMA_(a2, bfrag[3][2], acc[MB][3]);                      \
        acc[MB][0] = MFMA_(a3, bfrag[0][3], acc[MB][0]);                      \
        acc[MB][1] = MFMA_(a3, bfrag[1][3], acc[MB][1]);                      \
        acc[MB][2] = MFMA_(a3, bfrag[2][3], acc[MB][2]);                      \
        acc[MB][3] = MFMA_(a3, bfrag[3][3], acc[MB][3]);                      \
        /* activations for AB (accs filled one interval ago) */               \
        float own = (quad == 0) ? acc[AB][0][0]                               \
                  : (quad == 1) ? acc[AB][1][0]                               \
                  : (quad == 2) ? acc[AB][2][0] : acc[AB][3][0];              \
        float val = RCP_(1.f + __expf(-scale * own));                         \
        float res = fmaf(val, postm, posta);                                  \
        int ri = __float_as_int(res);                                         \
        float si = __int_as_float(__builtin_amdgcn_ds_bpermute(ad0, ri));     \
        float sf = __int_as_float(__builtin_amdgcn_ds_bpermute(ad1, ri));     \
        float tg = __int_as_float(__builtin_amdgcn_ds_bpermute(ad2, ri));     \
        float so = __int_as_float(__builtin_amdgcn_ds_bpermute(ad3, ri));     \
        c2[AB] = sf * c2[AB] + si * tg;                                       \
        float tcv = fmaf(RCP_(1.f + __expf(-2.f * c2[AB])), 2.f, -1.f);       \
        float h = so * tcv;                                                   \
        unsigned hr;                                                          \
        asm("v_cvt_pk_bf16_f32 %0, %1, %2" : "=v"(hr) : "v"(h), "v"(h));      \
        if (quad == 0) {                                                      \
            hbuf[AB][WP][j] = (unsigned short)hr;                             \
            *hp2[AB] = h;                                                     \
        }                                                                     \
        hp2[AB] += H_;                                                        \
        acc[AB][0][0] = pf[AB][SLOT][0];                                      \
        acc[AB][1][0] = pf[AB][SLOT][1];                                      \
        acc[AB][2][0] = pf[AB][SLOT][2];                                      \
        acc[AB][3][0] = pf[AB][SLOT][3];                                      \
        pf[AB][SLOT][0] = gp2[AB][0];                                         \
        pf[AB][SLOT][1] = gp2[AB][128];                                       \
        pf[AB][SLOT][2] = gp2[AB][256];                                       \
        pf[AB][SLOT][3] = gp2[AB][384];                                       \
        gp2[AB] += G4_;                                                       \
        asm volatile("s_waitcnt lgkmcnt(0)\n\ts_barrier" ::: "memory");       \
    }

    // Plane algebra: h_X(t) lives in hbuf[X][(t+1)&1]; MFMA_X(s) reads plane
    // s&1. Unroll t by 4 so planes/slots are compile-time constants.
    for (int t0 = 0; t0 < L_; t0 += 4) {
        INTERVAL(0, 1, 0, 1, 1)   // t=t0+0: MFMA0(t) | act1(t)
        INTERVAL(1, 0, 1, 1, 1)   //          MFMA1(t+1) | act0(t)
        INTERVAL(0, 1, 1, 0, 2)   // t=t0+1
        INTERVAL(1, 0, 0, 0, 2)
        INTERVAL(0, 1, 0, 1, 3)   // t=t0+2
        INTERVAL(1, 0, 1, 1, 3)
        INTERVAL(0, 1, 1, 0, 0)   // t=t0+3
        INTERVAL(1, 0, 0, 0, 0)
    }
    // No epilogue: act1(L-1) ran in the last A-interval, act0(L-1) in the
    // last B-interval; the final MFMA1(L) is harmless (preact ring reads up
    // to gx row L+4 -- inside d_out's unused upper half; result discarded).
#undef INTERVAL
#undef RCP_
#undef MFMA_
}

// ---------------------------------------------------------------------------
// Launch. Workspace layout (bytes):
//   rep : [0, 16 MiB)            8192 x 512 fp32
//   x   : [16 MiB, 32 MiB)       16 x 2048 x 128 fp32
//   hs  : [32 MiB, 48 MiB)       16 x 2048 x 128 fp32
//   off : [48 MiB, +32 KiB)      16 x 512 int
// gx (64 MiB) staged in d_out (128 MiB), consumed before the final GEMM;
// lstm_rec's prefetch may read <=5 rows past gx -- still inside d_out.
// ---------------------------------------------------------------------------
extern "C" void kernel_launch(void* const* d_in, const int* in_sizes, int n_in,
                              void* d_out, int out_size, void* d_ws, size_t ws_size,
                              hipStream_t stream)
{
    (void)in_sizes; (void)n_in; (void)out_size; (void)ws_size;
    const float* dec_hidden = (const float*)d_in[0];
    const int*   ids        = (const int*)d_in[1];
    const int*   lens       = (const int*)d_in[2];
    const float* char_emb   = (const float*)d_in[3];
    const float* W_proj     = (const float*)d_in[4];
    const float* b_proj     = (const float*)d_in[5];
    const float* W_ih       = (const float*)d_in[6];
    const float* W_hh       = (const float*)d_in[7];
    const float* b_ih       = (const float*)d_in[8];
    const float* b_hh       = (const float*)d_in[9];
    const float* W_pred     = (const float*)d_in[10];
    const float* b_pred     = (const float*)d_in[11];
    float* out = (float*)d_out;

    char* ws   = (char*)d_ws;
    float* rep = (float*)(ws);
    float* x   = (float*)(ws + (size_t)16 * 1024 * 1024);
    float* hs  = (float*)(ws + (size_t)32 * 1024 * 1024);
    int*   off = (int*)  (ws + (size_t)48 * 1024 * 1024);
    float* gx  = out;   // staged in output buffer, consumed before final GEMM

    // 1) rep = dec_hidden @ W_proj + b_proj   [8192,768]x[768,512]
    gemm_f32<false><<<dim3(4, 64), 256, 0, stream>>>(
        dec_hidden, W_proj, b_proj, nullptr, rep, B_ * N_, 512, DIM_);

    // 2) per-batch exclusive scan of word lengths
    scan_lens<<<B_, 512, 0, stream>>>(lens, off);

    // 3) build x = concat(char_emb[ids], 0-pad) then scatter rep into the pad
    char_gather<<<(B_ * L_) / 8, 256, 0, stream>>>(ids, char_emb, x);
    scatter_pad<<<B_ * N_, 512, 0, stream>>>(rep, lens, off, x);

    // 4) gx = x @ W_ih^T + b_ih + b_hh        [32768,128]x[512,128]^T
    gemm_f32<true><<<dim3(4, 256), 256, 0, stream>>>(
        x, W_ih, b_ih, b_hh, gx, B_ * L_, G4_, XDIM_);

    // 5) sequential LSTM (the critical path): 2-batch interleave, 8 blocks
    lstm_rec<<<B_ / 2, 512, 0, stream>>>(gx, W_hh, hs);

    // 6) out = hs @ W_pred + b_pred           [32768,128]x[128,1024]
    gemm_f32<false><<<dim3(8, 256), 256, 0, stream>>>(
        hs, W_pred, b_pred, nullptr, out, B_ * L_, VOCAB_, H_);
}